// Round 1
// baseline (307.619 us; speedup 1.0000x reference)
//
#include <hip/hip_runtime.h>
#include <hip/hip_bf16.h>
#include <cstddef>

#define NN 50000
#define EE 800000
#define TE 850000   // EE + NN self loops
#define INC 256
#define C1 128      // heads(2) * hid(64)
#define C2 64
#define NCHUNK 49   // ceil(NN/1024)

#define NB_COUNT 3321   // ceil(TE/256)
#define NB_GEMM1 782    // 391*2 (128x128 tiles over 50000x256)
#define NB_K1    (NB_GEMM1 + NB_COUNT)
#define NB_Z     196    // ceil(NN/256) zero blocks in prep0
#define NB_PREP0 (NB_Z + 256 + 128)

#define LOG2E 1.44269504088896340736f

typedef unsigned short ushort_t;
typedef short bf16x8 __attribute__((ext_vector_type(8)));
typedef float f32x4 __attribute__((ext_vector_type(4)));

__device__ inline ushort_t bf16r(float f) {  // RNE float->bf16
    unsigned u = __float_as_uint(f);
    unsigned r = (u + 0x7fffu + ((u >> 16) & 1u)) >> 16;
    return (ushort_t)r;
}
__device__ inline unsigned packbf2(float a, float b) {
    return (unsigned)bf16r(a) | ((unsigned)bf16r(b) << 16);
}
#define LOF(u) (__uint_as_float((u) << 16))           // low bf16 of packed uint
#define HIF(u) (__uint_as_float((u) & 0xffff0000u))   // high bf16 of packed uint
#define ELU(t) ((t) > 0.f ? (t) : (__expf(t) - 1.f))

__device__ inline void unpack8(const uint4& u, float f[8]) {
    f[0] = LOF(u.x); f[1] = HIF(u.x);
    f[2] = LOF(u.y); f[3] = HIF(u.y);
    f[4] = LOF(u.z); f[5] = HIF(u.z);
    f[6] = LOF(u.w); f[7] = HIF(u.w);
}

// ---------------- scans (serial dependency, small) ----------------

__global__ void k_scan1(const int* __restrict__ deg, int* __restrict__ incl,
                        int* __restrict__ totals) {
    __shared__ int lds[1024];
    int t = threadIdx.x;
    int i = blockIdx.x * 1024 + t;
    int v = (i < NN) ? deg[i] : 0;
    lds[t] = v;
    __syncthreads();
    for (int off = 1; off < 1024; off <<= 1) {
        int add = (t >= off) ? lds[t - off] : 0;
        __syncthreads();
        lds[t] += add;
        __syncthreads();
    }
    if (i < NN) incl[i] = lds[t];
    if (t == 1023) totals[blockIdx.x] = lds[t];
}

__global__ void k_scan3(const int* __restrict__ incl, const int* __restrict__ deg,
                        const int* __restrict__ totals, int* __restrict__ rowstart) {
    int i = blockIdx.x * blockDim.x + threadIdx.x;
    if (i == 0) rowstart[NN] = TE;
    if (i >= NN) return;
    int chunk = blockIdx.x >> 2;  // 256-thread blocks, 1024-wide chunks
    int coff = 0;
    for (int c = 0; c < chunk; c++) coff += totals[c];
    rowstart[i] = incl[i] - deg[i] + coff;
}

// ---------------- prep0: zero deg | prep W1 | prep W2 (replaces memset) ----------------

__global__ __launch_bounds__(256) void k_prep0(
    int* __restrict__ deg,
    const float* __restrict__ W1l, const float* __restrict__ W1r,
    const float* __restrict__ b1l, const float* __restrict__ b1r,
    ushort_t* __restrict__ Wt1, float* __restrict__ biasf1,
    const float* __restrict__ W2l, const float* __restrict__ W2r,
    const float* __restrict__ b2l, const float* __restrict__ b2r,
    ushort_t* __restrict__ Wt2, float* __restrict__ biasf2) {
    int b = blockIdx.x, tid = threadIdx.x;
    if (b < NB_Z) {
        int i = b * 256 + tid;
        if (i < NN) deg[i] = 0;
    } else if (b < NB_Z + 256) {
        // prep W1: Wt1[n][k], n in [0,256), K=256, HALF=128
        int n = b - NB_Z;
        int k = tid;
        const float* W = (n < 128) ? W1l : W1r;
        int c = (n < 128) ? n : n - 128;
        Wt1[(size_t)n * 256 + k] = bf16r(W[(size_t)k * 128 + c]);
        if (n == 0) biasf1[k] = (k < 128) ? b1l[k] : b1r[k - 128];
    } else {
        // prep W2: Wt2[n][k], n in [0,128), K=128, HALF=64
        int n = b - NB_Z - 256;
        int k = tid;
        if (k < 128) {
            const float* W = (n < 64) ? W2l : W2r;
            int c = (n < 64) ? n : n - 64;
            Wt2[(size_t)n * 128 + k] = bf16r(W[(size_t)k * 64 + c]);
            if (n == 0) biasf2[k] = (k < 64) ? b2l[k] : b2r[k - 64];
        }
    }
}

// ---------------- bf16 MFMA GEMM body ----------------
// C[M,NCOL](bf16) = A[M,K] @ Bt[NCOL,K]^T + bias(fp32)
// A either bf16 (AF32=false) or fp32 converted during LDS staging (AF32=true).
// 128x128 tile, BK=32, 256 threads, 16x16x32 MFMA; LDS rows padded to 40 bf16.

template <int K, int NCOL, bool AF32>
__device__ inline void gemm_body(const void* __restrict__ Aptr,
                                 const ushort_t* __restrict__ Bt,
                                 const float* __restrict__ bias,
                                 ushort_t* __restrict__ C, int M,
                                 int bm, int bn, ushort_t* As, ushort_t* Bs) {
    int tid = threadIdx.x;
    int w = tid >> 6, l = tid & 63;
    int wm = (w & 1) * 64, wn = (w >> 1) * 64;
    int lm = l & 15, half = l >> 4;

    f32x4 zero = {0.f, 0.f, 0.f, 0.f};
    f32x4 acc[4][4];
#pragma unroll
    for (int a = 0; a < 4; a++)
#pragma unroll
        for (int b = 0; b < 4; b++) acc[a][b] = zero;

    for (int k0 = 0; k0 < K; k0 += 32) {
#pragma unroll
        for (int q = 0; q < 2; q++) {
            int seg = q * 256 + tid;
            int mrow = seg >> 2;
            int ko = (seg & 3) * 8;
            if constexpr (AF32) {
                const float* A = (const float*)Aptr;
                int r = bm + mrow;
                if (r > M - 1) r = M - 1;  // fp32 input has no row padding
                const float* ap = &A[(size_t)r * K + k0 + ko];
                float4 lo = *(const float4*)ap;
                float4 hi = *(const float4*)(ap + 4);
                uint4 pk;
                pk.x = packbf2(lo.x, lo.y); pk.y = packbf2(lo.z, lo.w);
                pk.z = packbf2(hi.x, hi.y); pk.w = packbf2(hi.z, hi.w);
                *(uint4*)&As[mrow * 40 + ko] = pk;
            } else {
                const ushort_t* A = (const ushort_t*)Aptr;
                *(float4*)&As[mrow * 40 + ko] =
                    *(const float4*)&A[(size_t)(bm + mrow) * K + k0 + ko];
            }
            *(float4*)&Bs[mrow * 40 + ko] = *(const float4*)&Bt[(size_t)(bn + mrow) * K + k0 + ko];
        }
        __syncthreads();
        bf16x8 af[4], bfr[4];
#pragma unroll
        for (int mi = 0; mi < 4; mi++)
            af[mi] = *(const bf16x8*)&As[(wm + mi * 16 + lm) * 40 + half * 8];
#pragma unroll
        for (int ni = 0; ni < 4; ni++)
            bfr[ni] = *(const bf16x8*)&Bs[(wn + ni * 16 + lm) * 40 + half * 8];
#pragma unroll
        for (int mi = 0; mi < 4; mi++)
#pragma unroll
            for (int ni = 0; ni < 4; ni++)
                acc[mi][ni] = __builtin_amdgcn_mfma_f32_16x16x32_bf16(
                    af[mi], bfr[ni], acc[mi][ni], 0, 0, 0);
        __syncthreads();
    }
#pragma unroll
    for (int ni = 0; ni < 4; ni++) {
        int col = bn + wn + ni * 16 + lm;
        float bv = bias[col];
#pragma unroll
        for (int mi = 0; mi < 4; mi++) {
            int rbase = bm + wm + mi * 16 + half * 4;
#pragma unroll
            for (int r = 0; r < 4; r++) {
                int row = rbase + r;
                if (row < M) C[(size_t)row * NCOL + col] = bf16r(acc[mi][ni][r] + bv);
            }
        }
    }
}

// ---------------- K1: GEMM layer-1 (fp32 A) | count+rank (atomic wall hides gemm) ----------------

__global__ __launch_bounds__(256) void k_stage1(
    const int* __restrict__ ei, int* __restrict__ deg, int* __restrict__ rank,
    const float* __restrict__ x, const ushort_t* __restrict__ Wt1,
    const float* __restrict__ biasf1, ushort_t* __restrict__ xlr1) {
    int b = blockIdx.x;
    if (b < NB_GEMM1) {
        __shared__ __align__(16) ushort_t As[128 * 40];
        __shared__ __align__(16) ushort_t Bs[128 * 40];
        int bm = (b >> 1) * 128;
        int bn = (b & 1) * 128;
        gemm_body<256, 256, true>(x, Wt1, biasf1, xlr1, NN, bm, bn, As, Bs);
    } else {
        int e = (b - NB_GEMM1) * 256 + threadIdx.x;
        if (e < TE) {
            int dst = (e < EE) ? ei[EE + e] : (e - EE);
            rank[e] = atomicAdd(&deg[dst], 1);
        }
    }
}

// ---------------- scatter (atomic-free: precomputed rank) ----------------

__global__ __launch_bounds__(256) void k_scatter(
    const int* __restrict__ ei, const int* __restrict__ rank,
    const int* __restrict__ rowstart, int* __restrict__ ssrc) {
    int e = blockIdx.x * 256 + threadIdx.x;
    if (e < TE) {
        int s, d;
        if (e < EE) { s = ei[e]; d = ei[EE + e]; }
        else        { s = e - EE; d = s; }
        ssrc[rowstart[d] + rank[e]] = s;
    }
}

__global__ __launch_bounds__(256) void k_gemm2(
    const ushort_t* __restrict__ A, const ushort_t* __restrict__ Bt,
    const float* __restrict__ bias, ushort_t* __restrict__ C) {
    __shared__ __align__(16) ushort_t As[128 * 40];
    __shared__ __align__(16) ushort_t Bs[128 * 40];
    int bm = blockIdx.x * 128;
    gemm_body<128, 128, false>(A, Bt, bias, C, NN, bm, 0, As, Bs);
}

// ---------------- Fused GATv2 layer 1 ----------------
// 8 channels/lane (uint4 16B gathers), 16 lanes/edge, 4 edges in flight.
// att*lrelu(t) = (0.6att)t + (0.4att)|t|; att pre-scaled by log2e so p=exp2f(d).
// 32-bit byte offsets (50000*512 < 2^32) -> saddr-form global loads.

__global__ __launch_bounds__(256) void k_fused1(
    const ushort_t* __restrict__ xlr, const int* __restrict__ rowstart,
    const int* __restrict__ ssrc, const float* __restrict__ att,
    const float* __restrict__ bias,
    const float* __restrict__ g, const float* __restrict__ b,
    const float* __restrict__ m, const float* __restrict__ v,
    ushort_t* __restrict__ out) {
    int lane = threadIdx.x & 63;
    int i = blockIdx.x * 4 + (threadIdx.x >> 6);
    if (i >= NN) return;
    int slot = lane >> 4;   // 4 edge slots
    int c8 = lane & 15;     // 16 groups x 8 ch = 128
    const char* xb = (const char*)xlr;
    unsigned coff = (unsigned)c8 << 4;
    float xr[8];
    { uint4 u = *(const uint4*)(xb + (((unsigned)i << 9) + 256u + coff)); unpack8(u, xr); }
    float a6[8], a4[8];
    {
        const float* ap = att + 8 * c8;
#pragma unroll
        for (int c = 0; c < 8; c++) {
            float a = ap[c];
            a6[c] = a * (0.6f * LOG2E);
            a4[c] = a * (0.4f * LOG2E);
        }
    }
    int row = rowstart[i], end = rowstart[i + 1];
    float acc[8] = {0.f, 0.f, 0.f, 0.f, 0.f, 0.f, 0.f, 0.f};
    float s = 0.f;
    int j = row;
    for (; j + 16 <= end; j += 16) {
        int src[4];
        uint4 u[4];
#pragma unroll
        for (int k = 0; k < 4; k++) src[k] = ssrc[j + 4 * k + slot];
#pragma unroll
        for (int k = 0; k < 4; k++)
            u[k] = *(const uint4*)(xb + (((unsigned)src[k] << 9) + coff));
#pragma unroll
        for (int k = 0; k < 4; k++) {
            float f[8];
            unpack8(u[k], f);
            float t0 = f[0] + xr[0];
            float dd = fmaf(a6[0], t0, a4[0] * fabsf(t0));
#pragma unroll
            for (int c = 1; c < 8; c++) {
                float t = f[c] + xr[c];
                dd = fmaf(a6[c], t, fmaf(a4[c], fabsf(t), dd));
            }
            dd += __shfl_xor(dd, 1, 64);
            dd += __shfl_xor(dd, 2, 64);
            dd += __shfl_xor(dd, 4, 64);
            float p = exp2f(dd);
            s += p;
#pragma unroll
            for (int c = 0; c < 8; c++) acc[c] = fmaf(p, f[c], acc[c]);
        }
    }
    for (; j < end; j += 4) {
        int je = j + slot;
        bool valid = je < end;
        int src = valid ? ssrc[je] : i;
        uint4 uu = *(const uint4*)(xb + (((unsigned)src << 9) + coff));
        float f[8];
        unpack8(uu, f);
        float t0 = f[0] + xr[0];
        float dd = fmaf(a6[0], t0, a4[0] * fabsf(t0));
#pragma unroll
        for (int c = 1; c < 8; c++) {
            float t = f[c] + xr[c];
            dd = fmaf(a6[c], t, fmaf(a4[c], fabsf(t), dd));
        }
        dd += __shfl_xor(dd, 1, 64);
        dd += __shfl_xor(dd, 2, 64);
        dd += __shfl_xor(dd, 4, 64);
        float p = valid ? exp2f(dd) : 0.f;
        s += p;
#pragma unroll
        for (int c = 0; c < 8; c++) acc[c] = fmaf(p, f[c], acc[c]);
    }
    // combine the 4 edge slots (butterfly: all lanes get totals)
#pragma unroll
    for (int o = 16; o <= 32; o <<= 1) {
#pragma unroll
        for (int c = 0; c < 8; c++) acc[c] += __shfl_xor(acc[c], o, 64);
        s += __shfl_xor(s, o, 64);
    }
    if (slot == 0) {
        float inv = 1.f / s;
        const float* bp = bias + 8 * c8;
        const float* mp = m + 8 * c8;
        const float* vp = v + 8 * c8;
        const float* gp = g + 8 * c8;
        const float* b2p = b + 8 * c8;
        unsigned ov[4];
#pragma unroll
        for (int c = 0; c < 8; c += 2) {
            float o0 = acc[c] * inv + bp[c];
            float o1 = acc[c + 1] * inv + bp[c + 1];
            o0 = (o0 - mp[c]) * rsqrtf(vp[c] + 1e-5f) * gp[c] + b2p[c];
            o1 = (o1 - mp[c + 1]) * rsqrtf(vp[c + 1] + 1e-5f) * gp[c + 1] + b2p[c + 1];
            o0 = ELU(o0); o1 = ELU(o1);
            ov[c >> 1] = (unsigned)bf16r(o0) | ((unsigned)bf16r(o1) << 16);
        }
        uint4 w4;
        w4.x = ov[0]; w4.y = ov[1]; w4.z = ov[2]; w4.w = ov[3];
        *(uint4*)((char*)out + (((unsigned)i << 8) + coff)) = w4;
    }
}

// ---------------- Fused GATv2 layer 2 + classifier ----------------
// 8 channels/lane, 8 lanes/edge, 8 edges in flight.

__global__ __launch_bounds__(256) void k_fused2(
    const ushort_t* __restrict__ xlr, const int* __restrict__ rowstart,
    const int* __restrict__ ssrc, const float* __restrict__ att,
    const float* __restrict__ bias,
    const float* __restrict__ g, const float* __restrict__ b,
    const float* __restrict__ m, const float* __restrict__ v,
    const float* __restrict__ Wc, const float* __restrict__ bc,
    float* __restrict__ out) {
    int lane = threadIdx.x & 63;
    int i = blockIdx.x * 4 + (threadIdx.x >> 6);
    if (i >= NN) return;
    int slot = lane >> 3;   // 8 edge slots
    int c8 = lane & 7;      // 8 groups x 8 ch = 64
    const char* xb = (const char*)xlr;
    unsigned coff = (unsigned)c8 << 4;
    float xr[8];
    { uint4 u = *(const uint4*)(xb + (((unsigned)i << 8) + 128u + coff)); unpack8(u, xr); }
    float a6[8], a4[8];
    {
        const float* ap = att + 8 * c8;
#pragma unroll
        for (int c = 0; c < 8; c++) {
            float a = ap[c];
            a6[c] = a * (0.6f * LOG2E);
            a4[c] = a * (0.4f * LOG2E);
        }
    }
    int row = rowstart[i], end = rowstart[i + 1];
    float acc[8] = {0.f, 0.f, 0.f, 0.f, 0.f, 0.f, 0.f, 0.f};
    float s = 0.f;
    int j = row;
    for (; j + 16 <= end; j += 16) {
        int src[2];
        uint4 u[2];
#pragma unroll
        for (int k = 0; k < 2; k++) src[k] = ssrc[j + 8 * k + slot];
#pragma unroll
        for (int k = 0; k < 2; k++)
            u[k] = *(const uint4*)(xb + (((unsigned)src[k] << 8) + coff));
#pragma unroll
        for (int k = 0; k < 2; k++) {
            float f[8];
            unpack8(u[k], f);
            float t0 = f[0] + xr[0];
            float dd = fmaf(a6[0], t0, a4[0] * fabsf(t0));
#pragma unroll
            for (int c = 1; c < 8; c++) {
                float t = f[c] + xr[c];
                dd = fmaf(a6[c], t, fmaf(a4[c], fabsf(t), dd));
            }
            dd += __shfl_xor(dd, 1, 64);
            dd += __shfl_xor(dd, 2, 64);
            dd += __shfl_xor(dd, 4, 64);
            float p = exp2f(dd);
            s += p;
#pragma unroll
            for (int c = 0; c < 8; c++) acc[c] = fmaf(p, f[c], acc[c]);
        }
    }
    for (; j < end; j += 8) {
        int je = j + slot;
        bool valid = je < end;
        int src = valid ? ssrc[je] : i;
        uint4 uu = *(const uint4*)(xb + (((unsigned)src << 8) + coff));
        float f[8];
        unpack8(uu, f);
        float t0 = f[0] + xr[0];
        float dd = fmaf(a6[0], t0, a4[0] * fabsf(t0));
#pragma unroll
        for (int c = 1; c < 8; c++) {
            float t = f[c] + xr[c];
            dd = fmaf(a6[c], t, fmaf(a4[c], fabsf(t), dd));
        }
        dd += __shfl_xor(dd, 1, 64);
        dd += __shfl_xor(dd, 2, 64);
        dd += __shfl_xor(dd, 4, 64);
        float p = valid ? exp2f(dd) : 0.f;
        s += p;
#pragma unroll
        for (int c = 0; c < 8; c++) acc[c] = fmaf(p, f[c], acc[c]);
    }
    // combine the 8 edge slots
#pragma unroll
    for (int o = 8; o <= 32; o <<= 1) {
#pragma unroll
        for (int c = 0; c < 8; c++) acc[c] += __shfl_xor(acc[c], o, 64);
        s += __shfl_xor(s, o, 64);
    }
    float inv = 1.f / s;
    const float* bp = bias + 8 * c8;
    const float* mp = m + 8 * c8;
    const float* vp = v + 8 * c8;
    const float* gp = g + 8 * c8;
    const float* b2p = b + 8 * c8;
    const float* wp = Wc + 8 * c8;
    float z = 0.f;
#pragma unroll
    for (int c = 0; c < 8; c++) {
        float o0 = acc[c] * inv + bp[c];
        o0 = (o0 - mp[c]) * rsqrtf(vp[c] + 1e-5f) * gp[c] + b2p[c];
        o0 = ELU(o0);
        z = fmaf(o0, wp[c], z);
    }
    z += __shfl_xor(z, 1, 64);
    z += __shfl_xor(z, 2, 64);
    z += __shfl_xor(z, 4, 64);
    if (lane == 0) out[i] = 1.f / (1.f + __expf(-(z + bc[0])));
}

// ---------------- launch ----------------

extern "C" void kernel_launch(void* const* d_in, const int* in_sizes, int n_in,
                              void* d_out, int out_size, void* d_ws, size_t ws_size,
                              hipStream_t stream) {
    const float* x    = (const float*)d_in[0];
    const int*   ei   = (const int*)d_in[1];
    const float* W1l  = (const float*)d_in[2];
    const float* b1l  = (const float*)d_in[3];
    const float* W1r  = (const float*)d_in[4];
    const float* b1r  = (const float*)d_in[5];
    const float* att1 = (const float*)d_in[6];
    const float* bias1= (const float*)d_in[7];
    const float* bn1g = (const float*)d_in[8];
    const float* bn1b = (const float*)d_in[9];
    const float* bn1m = (const float*)d_in[10];
    const float* bn1v = (const float*)d_in[11];
    const float* W2l  = (const float*)d_in[12];
    const float* b2l  = (const float*)d_in[13];
    const float* W2r  = (const float*)d_in[14];
    const float* b2r  = (const float*)d_in[15];
    const float* att2 = (const float*)d_in[16];
    const float* bias2= (const float*)d_in[17];
    const float* bn2g = (const float*)d_in[18];
    const float* bn2b = (const float*)d_in[19];
    const float* bn2m = (const float*)d_in[20];
    const float* bn2v = (const float*)d_in[21];
    const float* Wc   = (const float*)d_in[22];
    const float* bc   = (const float*)d_in[23];
    float* out = (float*)d_out;

    char* ws = (char*)d_ws;
    size_t off = 0;
    auto alloc = [&](size_t bytes) {
        size_t o = off;
        off += (bytes + 255) & ~(size_t)255;
        return o;
    };
    ushort_t* xlr1  = (ushort_t*)(ws + alloc((size_t)NN * 256 * 2));  // reused as xlr2
    ushort_t* h1b   = (ushort_t*)(ws + alloc((size_t)(NN + 128) * 128 * 2));
    ushort_t* Wt1   = (ushort_t*)(ws + alloc((size_t)256 * 256 * 2));
    float*    biasf1= (float*)(ws + alloc(256 * 4));
    ushort_t* Wt2   = (ushort_t*)(ws + alloc((size_t)128 * 128 * 2));
    float*    biasf2= (float*)(ws + alloc(128 * 4));
    int* deg      = (int*)(ws + alloc((size_t)NN * 4));
    int* incl     = (int*)(ws + alloc((size_t)NN * 4));
    int* rowstart = (int*)(ws + alloc((size_t)(NN + 1) * 4));
    int* totals   = (int*)(ws + alloc(64 * 4));
    int* rank     = (int*)(ws + alloc((size_t)TE * 4));
    int* ssrc     = (int*)(ws + alloc((size_t)TE * 4));
    ushort_t* xlr2 = xlr1;

    // prep0: zero deg | prep W1 | prep W2 (replaces memset + prep stages)
    k_prep0<<<NB_PREP0, 256, 0, stream>>>(deg, W1l, W1r, b1l, b1r, Wt1, biasf1,
                                          W2l, W2r, b2l, b2r, Wt2, biasf2);

    // K1: GEMM layer-1 directly from fp32 x | count+rank (gemm hidden under atomic wall)
    k_stage1<<<NB_K1, 256, 0, stream>>>(ei, deg, rank, x, Wt1, biasf1, xlr1);

    // scans (serial, small)
    k_scan1<<<NCHUNK, 1024, 0, stream>>>(deg, incl, totals);
    k_scan3<<<(NN + 255) / 256, 256, 0, stream>>>(incl, deg, totals, rowstart);

    // scatter (atomic-free)
    k_scatter<<<NB_COUNT, 256, 0, stream>>>(ei, rank, rowstart, ssrc);

    // layer 1 fused
    k_fused1<<<(NN + 3) / 4, 256, 0, stream>>>(xlr1, rowstart, ssrc, att1, bias1,
                                               bn1g, bn1b, bn1m, bn1v, h1b);

    // layer 2 (+classifier)
    k_gemm2<<<(NN + 127) / 128, 256, 0, stream>>>(h1b, Wt2, biasf2, xlr2);
    k_fused2<<<(NN + 3) / 4, 256, 0, stream>>>(xlr2, rowstart, ssrc, att2, bias2,
                                               bn2g, bn2b, bn2m, bn2v, Wc, bc, out);
}